// Round 11
// baseline (455.519 us; speedup 1.0000x reference)
//
#include <hip/hip_runtime.h>
#include <hip/hip_bf16.h>

#define N_NODES 8192
#define IN_F    256
#define OUT_F   64
#define ALPHA   0.3f
#define MBIAS   20.0f            // >= max dst_j; softmax exact after l-division
#define CSPL    8                // column splits
#define COLS_PER (N_NODES / CSPL)    // 1024
#define NTILES  (COLS_PER / 64)      // 16
#define LDP     72               // padded LDS row stride (u16): 64 + 8

typedef unsigned short u16;
typedef unsigned int   u32;
typedef __attribute__((ext_vector_type(8))) short bf16x8;
typedef __attribute__((ext_vector_type(4))) float f32x4;

__device__ __forceinline__ float bf2f(u32 u) { return __uint_as_float(u << 16); }
__device__ __forceinline__ u32 f2bfbits(float x) {          // RNE f32->bf16
    u32 u = __float_as_uint(x);
    return (u + 0x7FFFu + ((u >> 16) & 1u)) >> 16;
}
__device__ __forceinline__ float lrelu(float s) { return s > 0.f ? s : ALPHA * s; }

// dtype probe: adj[0,0] == 1.0 always. bf16 -> low16 of first word = 0x3F80.
__device__ __forceinline__ int detect_bf16(const void* adj) {
    return ((((const u32*)adj)[0] & 0xFFFFu) == 0x3F80u) ? 1 : 0;
}

template <bool BF16>
__device__ __forceinline__ float ld(const void* p, size_t idx) {
    if constexpr (BF16) return bf2f(((const u16*)p)[idx]);
    else                return ((const float*)p)[idx];
}

// ---------------------------------------------------------------------------
// Kernel 1: Wh = h @ W. 4 rows per wave (W read once per 4 rows), 16 rows
// per block. Emits WhT [64][8192] bf16 scratch, src/dst fp32. (R9-proven)
// ---------------------------------------------------------------------------
template <bool BF16>
__device__ __forceinline__ void wh4_impl(
    const void* __restrict__ h, const void* __restrict__ W,
    const void* __restrict__ a, float* __restrict__ src,
    float* __restrict__ dst, int i0, int lane, float* accv)
{
    float acc0 = 0.f, acc1 = 0.f, acc2 = 0.f, acc3 = 0.f;
#pragma unroll 8
    for (int k = 0; k < IN_F; ++k) {
        float wv = ld<BF16>(W, (size_t)k * OUT_F + lane);      // coalesced
        float h0 = ld<BF16>(h, (size_t)(i0 + 0) * IN_F + k);   // wave-uniform
        float h1 = ld<BF16>(h, (size_t)(i0 + 1) * IN_F + k);
        float h2 = ld<BF16>(h, (size_t)(i0 + 2) * IN_F + k);
        float h3 = ld<BF16>(h, (size_t)(i0 + 3) * IN_F + k);
        acc0 = fmaf(h0, wv, acc0);
        acc1 = fmaf(h1, wv, acc1);
        acc2 = fmaf(h2, wv, acc2);
        acc3 = fmaf(h3, wv, acc3);
    }
    float av = ld<BF16>(a, lane);
    float bv = ld<BF16>(a, OUT_F + lane);
    float accs[4] = {acc0, acc1, acc2, acc3};
#pragma unroll
    for (int r = 0; r < 4; ++r) {
        float ps = accs[r] * av, pd = accs[r] * bv;
#pragma unroll
        for (int off = 32; off > 0; off >>= 1) {
            ps += __shfl_xor(ps, off, 64);
            pd += __shfl_xor(pd, off, 64);
        }
        if (lane == 0) { src[i0 + r] = ps; dst[i0 + r] = pd; }
        accv[r] = accs[r];
    }
}

__global__ __launch_bounds__(256) void gat_wh_kernel(
    const void* __restrict__ h, const void* __restrict__ W,
    const void* __restrict__ a, const void* __restrict__ adj,
    u16* __restrict__ WhT, float* __restrict__ src, float* __restrict__ dst)
{
    __shared__ float accs[16][OUT_F];
    const int tid = threadIdx.x, wave = tid >> 6, lane = tid & 63;
    const int i0 = blockIdx.x * 16 + wave * 4;
    float av[4];
    if (detect_bf16(adj)) wh4_impl<true >(h, W, a, src, dst, i0, lane, av);
    else                  wh4_impl<false>(h, W, a, src, dst, i0, lane, av);
#pragma unroll
    for (int r = 0; r < 4; ++r) accs[wave * 4 + r][lane] = av[r];
    __syncthreads();
    if (tid < OUT_F) {                    // WhT[f][i0..i0+15], bf16 scratch
        u32 w[8];
#pragma unroll
        for (int e = 0; e < 8; ++e) {
            u32 lo = f2bfbits(accs[2 * e][tid]);
            u32 hi = f2bfbits(accs[2 * e + 1][tid]);
            w[e] = lo | (hi << 16);
        }
        u16* dstp = WhT + (size_t)tid * N_NODES + blockIdx.x * 16;
        *(uint4*)dstp       = *(uint4*)&w[0];
        *(uint4*)(dstp + 8) = *(uint4*)&w[4];
    }
}

// ---------------------------------------------------------------------------
// Kernel 2: fused adj-stream + masked-softmax @ Wh via MFMA.
// Block = 64 rows x 1024 cols; grid 128x8 tiles adj DISJOINTLY, so the
// prologue streams this block's 256 KB adj window directly (thread (r,cq)
// loads exactly the 16 cols/tile it later computes P for; 64 independent
// dwordx4 loads in 4 chunks) and keeps 16 per-tile 16-bit masks in 8 VGPRs.
// No mask buffer, no ballots, no extra barrier. K-loop = R10-proven:
// row-major (stride 72) LDS tiles, fragment A[m=lane&15][k=(lane>>4)*8+j]
// = one ds_read_b128, B-tile register prefetch, 2 barriers/tile.
// ---------------------------------------------------------------------------
__global__ __launch_bounds__(256, 4) void gat_attn_kernel(
    const void* __restrict__ adj, const u16* __restrict__ WhT,
    const float* __restrict__ src, const float* __restrict__ dst,
    float* __restrict__ O_part, float* __restrict__ l_part)
{
    __shared__ alignas(16) u16 Plds[64 * LDP];              // 9216 B
    __shared__ alignas(16) u16 Blds[64 * LDP];              // 9216 B

    const int tid = threadIdx.x, wave = tid >> 6, lane = tid & 63;
    const int r = tid >> 2, cq = tid & 3;     // row (P) / feat (B), 16-col chunk
    const int i0 = blockIdx.x * 64, c0 = blockIdx.y * COLS_PER;
    const int isbf = detect_bf16(adj);

    // ---- Phase 1: stream adj window, pack 16x16-bit masks into mp[8] ----
    u32 mp[8] = {0, 0, 0, 0, 0, 0, 0, 0};
    if (isbf) {
        const u16* arow = (const u16*)adj + (size_t)(i0 + r) * N_NODES + c0 + cq * 16;
#pragma unroll
        for (int ch = 0; ch < 4; ++ch) {
            uint4 v[8];
#pragma unroll
            for (int tt = 0; tt < 4; ++tt) {
                v[2 * tt]     = *(const uint4*)(arow + (ch * 4 + tt) * 64);
                v[2 * tt + 1] = *(const uint4*)(arow + (ch * 4 + tt) * 64 + 8);
            }
#pragma unroll
            for (int tt = 0; tt < 4; ++tt) {
                u32 ww[8] = {v[2*tt].x, v[2*tt].y, v[2*tt].z, v[2*tt].w,
                             v[2*tt+1].x, v[2*tt+1].y, v[2*tt+1].z, v[2*tt+1].w};
                u32 m16 = 0;
#pragma unroll
                for (int e = 0; e < 8; ++e) {
                    if (ww[e] & 0xFFFFu) m16 |= 1u << (2 * e);
                    if (ww[e] >> 16)     m16 |= 1u << (2 * e + 1);
                }
                int t = ch * 4 + tt;
                mp[t >> 1] |= m16 << (16 * (t & 1));
            }
        }
    } else {
        const float* arow = (const float*)adj + (size_t)(i0 + r) * N_NODES + c0 + cq * 16;
#pragma unroll
        for (int ch = 0; ch < 4; ++ch) {
            uint4 v[16];
#pragma unroll
            for (int tt = 0; tt < 4; ++tt)
#pragma unroll
                for (int q = 0; q < 4; ++q)
                    v[4 * tt + q] = *(const uint4*)(arow + (ch * 4 + tt) * 64 + q * 4);
#pragma unroll
            for (int tt = 0; tt < 4; ++tt) {
                u32 ww[16] = {v[4*tt].x,   v[4*tt].y,   v[4*tt].z,   v[4*tt].w,
                              v[4*tt+1].x, v[4*tt+1].y, v[4*tt+1].z, v[4*tt+1].w,
                              v[4*tt+2].x, v[4*tt+2].y, v[4*tt+2].z, v[4*tt+2].w,
                              v[4*tt+3].x, v[4*tt+3].y, v[4*tt+3].z, v[4*tt+3].w};
                u32 m16 = 0;
#pragma unroll
                for (int e = 0; e < 16; ++e)
                    if (ww[e]) m16 |= 1u << e;    // fp32 adj is exactly 0/1
                int t = ch * 4 + tt;
                mp[t >> 1] |= m16 << (16 * (t & 1));
            }
        }
    }

    // ---- Phase 2: K-loop (R10-proven) with msk from registers ----
    const float srow = src[i0 + r];
    const float m = lrelu(srow + MBIAS);      // upper bound of row max

    const u16*    whtrow = WhT + (size_t)r * N_NODES + c0 + cq * 16; // r = feat for B
    const float4* dstp   = (const float4*)(dst + c0 + cq * 16);

    const int mrow = lane & 15, kq = (lane >> 4) * 8;

    f32x4 acc[4] = {{0,0,0,0},{0,0,0,0},{0,0,0,0},{0,0,0,0}};
    float lacc = 0.f;

    uint4 pb0 = *(const uint4*)(whtrow);      // prologue B prefetch (tile 0)
    uint4 pb1 = *(const uint4*)(whtrow + 8);

    for (int t = 0; t < NTILES; ++t) {
        *(uint4*)&Blds[r * LDP + cq * 16]     = pb0;
        *(uint4*)&Blds[r * LDP + cq * 16 + 8] = pb1;

        u32 msk = (mp[t >> 1] >> (16 * (t & 1))) & 0xFFFFu;
        float4 d0 = dstp[t * 16],     d1 = dstp[t * 16 + 1];
        float4 d2 = dstp[t * 16 + 2], d3 = dstp[t * 16 + 3];
        float dv[16] = {d0.x,d0.y,d0.z,d0.w, d1.x,d1.y,d1.z,d1.w,
                        d2.x,d2.y,d2.z,d2.w, d3.x,d3.y,d3.z,d3.w};
        u32 po[8];
#pragma unroll
        for (int e = 0; e < 8; ++e) {
            float s0 = lrelu(srow + dv[2 * e]);
            float s1 = lrelu(srow + dv[2 * e + 1]);
            float p0 = (msk & (1u << (2 * e)))     ? __expf(s0 - m) : 0.f;
            float p1 = (msk & (1u << (2 * e + 1))) ? __expf(s1 - m) : 0.f;
            u32 q0 = f2bfbits(p0), q1 = f2bfbits(p1);
            lacc += bf2f(q0) + bf2f(q1);      // l from ROUNDED P
            po[e] = q0 | (q1 << 16);
        }
        *(uint4*)&Plds[r * LDP + cq * 16]     = *(uint4*)&po[0];
        *(uint4*)&Plds[r * LDP + cq * 16 + 8] = *(uint4*)&po[4];

        __syncthreads();

        if (t + 1 < NTILES) {                 // prefetch next B tile
            pb0 = *(const uint4*)(whtrow + (t + 1) * 64);
            pb1 = *(const uint4*)(whtrow + (t + 1) * 64 + 8);
        }

#pragma unroll
        for (int ks = 0; ks < 2; ++ks) {
            bf16x8 avf = *(bf16x8*)&Plds[(16 * wave + mrow) * LDP + ks * 32 + kq];
#pragma unroll
            for (int nt = 0; nt < 4; ++nt) {
                bf16x8 bvf = *(bf16x8*)&Blds[(16 * nt + mrow) * LDP + ks * 32 + kq];
                acc[nt] = __builtin_amdgcn_mfma_f32_16x16x32_bf16(avf, bvf, acc[nt], 0, 0, 0);
            }
        }
        __syncthreads();
    }

    // partial l: sum over the 4 col-chunk threads of each row
    lacc += __shfl_xor(lacc, 1, 64);
    lacc += __shfl_xor(lacc, 2, 64);
    if (cq == 0) l_part[blockIdx.y * N_NODES + i0 + r] = lacc;

    // C/D layout: col = lane&15, row = (lane>>4)*4 + reg   [m89/m91 verified]
    float* Ob = O_part + (size_t)blockIdx.y * N_NODES * OUT_F;
#pragma unroll
    for (int nt = 0; nt < 4; ++nt)
#pragma unroll
        for (int reg = 0; reg < 4; ++reg) {
            int row = i0 + 16 * wave + (lane >> 4) * 4 + reg;
            int col = 16 * nt + (lane & 15);
            Ob[(size_t)row * OUT_F + col] = acc[nt][reg];
        }
}

// ---------------------------------------------------------------------------
// Kernel 3: out = elu( (sum_c O_c) / (sum_c l_c) ), store per dtype.
// ---------------------------------------------------------------------------
__global__ __launch_bounds__(256) void gat_reduce_kernel(
    const float* __restrict__ O_part, const float* __restrict__ l_part,
    const void* __restrict__ adj, void* __restrict__ out)
{
    int gid = blockIdx.x * 256 + threadIdx.x;
    int i = gid >> 6;
    float O = 0.f, L = 0.f;
#pragma unroll
    for (int c = 0; c < CSPL; ++c) {
        O += O_part[(size_t)c * N_NODES * OUT_F + gid];
        L += l_part[c * N_NODES + i];
    }
    float hp = O / L;
    float o = hp > 0.f ? hp : expm1f(hp);     // elu alpha=1
    if (detect_bf16(adj)) ((u16*)out)[gid] = (u16)f2bfbits(o);
    else                  ((float*)out)[gid] = o;
}

// ---------------------------------------------------------------------------
extern "C" void kernel_launch(void* const* d_in, const int* in_sizes, int n_in,
                              void* d_out, int out_size, void* d_ws, size_t ws_size,
                              hipStream_t stream)
{
    const void* h   = d_in[0];
    const void* adj = d_in[1];
    const void* W   = d_in[2];
    const void* a   = d_in[3];

    char* ws = (char*)d_ws;
    u16*   WhT    = (u16*)ws;                                   // 1 MB
    float* src    = (float*)(ws + (1u << 20));                  // 32 KB
    float* dst    = (float*)(ws + (1u << 20) + 32768);          // 32 KB
    float* O_part = (float*)(ws + (2u << 20));                  // 16 MB (8 splits)
    float* l_part = (float*)(ws + (18u << 20));                 // 256 KB

    gat_wh_kernel<<<N_NODES / 16, 256, 0, stream>>>(h, W, a, adj, WhT, src, dst);
    dim3 grid(N_NODES / 64, CSPL);
    gat_attn_kernel<<<grid, 256, 0, stream>>>(adj, WhT, src, dst, O_part, l_part);
    gat_reduce_kernel<<<N_NODES * OUT_F / 256, 256, 0, stream>>>(O_part, l_part, adj, d_out);
}

// Round 12
// 436.432 us; speedup vs baseline: 1.0437x; 1.0437x over previous
//
#include <hip/hip_runtime.h>
#include <hip/hip_bf16.h>

#define N_NODES 8192
#define IN_F    256
#define OUT_F   64
#define ALPHA   0.3f
#define MBIAS   20.0f            // >= max dst_j; softmax exact after l-division
#define CSPL    32               // column splits
#define COLS_PER (N_NODES / CSPL)    // 256
#define BST     264              // Blds row stride (u16): 256 + 8

typedef unsigned short u16;
typedef unsigned int   u32;
typedef unsigned long long u64;
typedef __attribute__((ext_vector_type(8))) short bf16x8;
typedef __attribute__((ext_vector_type(4))) float f32x4;

__device__ __forceinline__ float bf2f(u32 u) { return __uint_as_float(u << 16); }
__device__ __forceinline__ u32 f2bfbits(float x) {          // RNE f32->bf16
    u32 u = __float_as_uint(x);
    return (u + 0x7FFFu + ((u >> 16) & 1u)) >> 16;
}
__device__ __forceinline__ float lrelu(float s) { return s > 0.f ? s : ALPHA * s; }

// dtype probe: adj[0,0] == 1.0 always. bf16 -> low16 of first word = 0x3F80.
__device__ __forceinline__ int detect_bf16(const void* adj) {
    return ((((const u32*)adj)[0] & 0xFFFFu) == 0x3F80u) ? 1 : 0;
}

template <bool BF16>
__device__ __forceinline__ float ld(const void* p, size_t idx) {
    if constexpr (BF16) return bf2f(((const u16*)p)[idx]);
    else                return ((const float*)p)[idx];
}

// ---------------------------------------------------------------------------
// Kernel 1: Wh = h @ W. 4 rows per wave (W read once per 4 rows), 16 rows
// per block. Emits WhT [64][8192] bf16 scratch, src/dst fp32. (R9-proven)
// ---------------------------------------------------------------------------
template <bool BF16>
__device__ __forceinline__ void wh4_impl(
    const void* __restrict__ h, const void* __restrict__ W,
    const void* __restrict__ a, float* __restrict__ src,
    float* __restrict__ dst, int i0, int lane, float* accv)
{
    float acc0 = 0.f, acc1 = 0.f, acc2 = 0.f, acc3 = 0.f;
#pragma unroll 8
    for (int k = 0; k < IN_F; ++k) {
        float wv = ld<BF16>(W, (size_t)k * OUT_F + lane);      // coalesced
        float h0 = ld<BF16>(h, (size_t)(i0 + 0) * IN_F + k);   // wave-uniform
        float h1 = ld<BF16>(h, (size_t)(i0 + 1) * IN_F + k);
        float h2 = ld<BF16>(h, (size_t)(i0 + 2) * IN_F + k);
        float h3 = ld<BF16>(h, (size_t)(i0 + 3) * IN_F + k);
        acc0 = fmaf(h0, wv, acc0);
        acc1 = fmaf(h1, wv, acc1);
        acc2 = fmaf(h2, wv, acc2);
        acc3 = fmaf(h3, wv, acc3);
    }
    float av = ld<BF16>(a, lane);
    float bv = ld<BF16>(a, OUT_F + lane);
    float accs[4] = {acc0, acc1, acc2, acc3};
#pragma unroll
    for (int r = 0; r < 4; ++r) {
        float ps = accs[r] * av, pd = accs[r] * bv;
#pragma unroll
        for (int off = 32; off > 0; off >>= 1) {
            ps += __shfl_xor(ps, off, 64);
            pd += __shfl_xor(pd, off, 64);
        }
        if (lane == 0) { src[i0 + r] = ps; dst[i0 + r] = pd; }
        accv[r] = accs[r];
    }
}

__global__ __launch_bounds__(256) void gat_wh_kernel(
    const void* __restrict__ h, const void* __restrict__ W,
    const void* __restrict__ a, const void* __restrict__ adj,
    u16* __restrict__ WhT, float* __restrict__ src, float* __restrict__ dst)
{
    __shared__ float accs[16][OUT_F];
    const int tid = threadIdx.x, wave = tid >> 6, lane = tid & 63;
    const int i0 = blockIdx.x * 16 + wave * 4;
    float av[4];
    if (detect_bf16(adj)) wh4_impl<true >(h, W, a, src, dst, i0, lane, av);
    else                  wh4_impl<false>(h, W, a, src, dst, i0, lane, av);
#pragma unroll
    for (int r = 0; r < 4; ++r) accs[wave * 4 + r][lane] = av[r];
    __syncthreads();
    if (tid < OUT_F) {                    // WhT[f][i0..i0+15], bf16 scratch
        u32 w[8];
#pragma unroll
        for (int e = 0; e < 8; ++e) {
            u32 lo = f2bfbits(accs[2 * e][tid]);
            u32 hi = f2bfbits(accs[2 * e + 1][tid]);
            w[e] = lo | (hi << 16);
        }
        u16* dstp = WhT + (size_t)tid * N_NODES + blockIdx.x * 16;
        *(uint4*)dstp       = *(uint4*)&w[0];
        *(uint4*)(dstp + 8) = *(uint4*)&w[4];
    }
}

// ---------------------------------------------------------------------------
// Kernel 2: fused adj-stream + masked-softmax @ Wh via MFMA.
// Block = 64 rows x 256 cols; grid 128x32 tiles adj disjointly.
// Prologue (one barrier total): stage B window (64x256 bf16) + dst window
// (256 f32) + adj->bitmask via LANE-STRIDED coalesced loads + __ballot
// (R9-proven pattern: p[lane], p[64+lane], ... = 256B/inst).
// K-loop (4 tiles): NO barriers, NO global loads. Each thread computes its
// A-fragment P values (row=lane&15, k=(lane>>4)*8+j) directly in registers
// from LDS mask word + LDS dst; B fragments read from prologue-staged LDS.
// ---------------------------------------------------------------------------
__global__ __launch_bounds__(256, 4) void gat_attn_kernel(
    const void* __restrict__ adj, const u16* __restrict__ WhT,
    const float* __restrict__ src, const float* __restrict__ dst,
    float* __restrict__ O_part, float* __restrict__ l_part)
{
    __shared__ alignas(16) u16  Blds[64 * BST];     // 33792 B
    __shared__ alignas(16) u64  Mlds[64 * 5];       // 2560 B (stride 5 u64 = 40B)
    __shared__ alignas(16) float Dlds[COLS_PER];    // 1024 B

    const int tid = threadIdx.x, wave = tid >> 6, lane = tid & 63;
    const int i0 = blockIdx.x * 64, c0 = blockIdx.y * COLS_PER;
    const int isbf = detect_bf16(adj);

    // ---- stage B window: thread (f=tid>>2, cq=tid&3) copies 64 cols ----
    {
        const u16* wrow = WhT + (size_t)(tid >> 2) * N_NODES + c0 + (tid & 3) * 64;
        u16* bl = &Blds[(tid >> 2) * BST + (tid & 3) * 64];
#pragma unroll
        for (int q = 0; q < 8; ++q)
            *(uint4*)(bl + q * 8) = *(const uint4*)(wrow + q * 8);
    }
    // ---- stage dst window (one coalesced inst) ----
    Dlds[tid] = dst[c0 + tid];

    // ---- stage adj bitmask: wave w handles rows 16w..16w+15 ----
    if (isbf) {
        const u16* base = (const u16*)adj;
#pragma unroll 4
        for (int rr = 0; rr < 16; ++rr) {
            const int row = wave * 16 + rr;
            const u16* p = base + (size_t)(i0 + row) * N_NODES + c0;
            u64 b0 = __ballot(p[lane]       != 0);   // 128B coalesced each
            u64 b1 = __ballot(p[64  + lane] != 0);
            u64 b2 = __ballot(p[128 + lane] != 0);
            u64 b3 = __ballot(p[192 + lane] != 0);
            u64 v = (lane == 0) ? b0 : (lane == 1) ? b1 : (lane == 2) ? b2 : b3;
            if (lane < 4) Mlds[row * 5 + lane] = v;
        }
    } else {
        const float* base = (const float*)adj;
#pragma unroll 4
        for (int rr = 0; rr < 16; ++rr) {
            const int row = wave * 16 + rr;
            const float* p = base + (size_t)(i0 + row) * N_NODES + c0;
            u64 b0 = __ballot(p[lane]       != 0.f); // 256B coalesced each
            u64 b1 = __ballot(p[64  + lane] != 0.f);
            u64 b2 = __ballot(p[128 + lane] != 0.f);
            u64 b3 = __ballot(p[192 + lane] != 0.f);
            u64 v = (lane == 0) ? b0 : (lane == 1) ? b1 : (lane == 2) ? b2 : b3;
            if (lane < 4) Mlds[row * 5 + lane] = v;
        }
    }

    __syncthreads();                       // the ONLY barrier

    const int mrow = lane & 15, kq = (lane >> 4) * 8;
    const int mloc = 16 * wave + mrow;     // block-local row this thread owns
    const float srow = src[i0 + mloc];
    const float mbound = lrelu(srow + MBIAS);   // upper bound of row max

    f32x4 acc[4] = {{0,0,0,0},{0,0,0,0},{0,0,0,0},{0,0,0,0}};
    float lacc = 0.f;

#pragma unroll
    for (int t = 0; t < 4; ++t) {
        const u64 mword = Mlds[mloc * 5 + t];    // 16 distinct b64/wave: conflict-free
#pragma unroll
        for (int ks = 0; ks < 2; ++ks) {
            const u32 bits = (u32)(mword >> (ks * 32 + kq)) & 0xFFu;
            const float* dp = &Dlds[t * 64 + ks * 32 + kq];
            float4 dd0 = *(const float4*)dp;          // broadcast b128 reads
            float4 dd1 = *(const float4*)(dp + 4);
            float dv[8] = {dd0.x,dd0.y,dd0.z,dd0.w, dd1.x,dd1.y,dd1.z,dd1.w};
            union { u32 w[4]; bf16x8 v; } pa;
#pragma unroll
            for (int e = 0; e < 4; ++e) {
                float s0 = lrelu(srow + dv[2 * e]);
                float s1 = lrelu(srow + dv[2 * e + 1]);
                float p0 = (bits & (1u << (2 * e)))     ? __expf(s0 - mbound) : 0.f;
                float p1 = (bits & (1u << (2 * e + 1))) ? __expf(s1 - mbound) : 0.f;
                u32 q0 = f2bfbits(p0), q1 = f2bfbits(p1);
                lacc += bf2f(q0) + bf2f(q1);     // l from ROUNDED P
                pa.w[e] = q0 | (q1 << 16);
            }
#pragma unroll
            for (int nt = 0; nt < 4; ++nt) {
                bf16x8 bvf = *(bf16x8*)&Blds[(16 * nt + mrow) * BST + t * 64 + ks * 32 + kq];
                acc[nt] = __builtin_amdgcn_mfma_f32_16x16x32_bf16(pa.v, bvf, acc[nt], 0, 0, 0);
            }
        }
    }

    // l: lanes {mrow, mrow+16, mrow+32, mrow+48} hold row mloc's partial sums
    lacc += __shfl_xor(lacc, 16, 64);
    lacc += __shfl_xor(lacc, 32, 64);
    if (lane < 16) l_part[blockIdx.y * N_NODES + i0 + 16 * wave + lane] = lacc;

    // C/D layout: col = lane&15, row = (lane>>4)*4 + reg   [m89/m91 verified]
    float* Ob = O_part + (size_t)blockIdx.y * N_NODES * OUT_F;
#pragma unroll
    for (int nt = 0; nt < 4; ++nt)
#pragma unroll
        for (int reg = 0; reg < 4; ++reg) {
            int row = i0 + 16 * wave + (lane >> 4) * 4 + reg;
            int col = 16 * nt + (lane & 15);
            Ob[(size_t)row * OUT_F + col] = acc[nt][reg];
        }
}

// ---------------------------------------------------------------------------
// Kernel 3: out = elu( (sum_c O_c) / (sum_c l_c) ), store per dtype.
// ---------------------------------------------------------------------------
__global__ __launch_bounds__(256) void gat_reduce_kernel(
    const float* __restrict__ O_part, const float* __restrict__ l_part,
    const void* __restrict__ adj, void* __restrict__ out)
{
    int gid = blockIdx.x * 256 + threadIdx.x;
    int i = gid >> 6;
    float O = 0.f, L = 0.f;
#pragma unroll 8
    for (int c = 0; c < CSPL; ++c) {
        O += O_part[(size_t)c * N_NODES * OUT_F + gid];
        L += l_part[c * N_NODES + i];
    }
    float hp = O / L;
    float o = hp > 0.f ? hp : expm1f(hp);     // elu alpha=1
    if (detect_bf16(adj)) ((u16*)out)[gid] = (u16)f2bfbits(o);
    else                  ((float*)out)[gid] = o;
}

// ---------------------------------------------------------------------------
extern "C" void kernel_launch(void* const* d_in, const int* in_sizes, int n_in,
                              void* d_out, int out_size, void* d_ws, size_t ws_size,
                              hipStream_t stream)
{
    const void* h   = d_in[0];
    const void* adj = d_in[1];
    const void* W   = d_in[2];
    const void* a   = d_in[3];

    char* ws = (char*)d_ws;
    u16*   WhT    = (u16*)ws;                                   // 1 MB
    float* src    = (float*)(ws + (1u << 20));                  // 32 KB
    float* dst    = (float*)(ws + (1u << 20) + 32768);          // 32 KB
    float* O_part = (float*)(ws + (2u << 20));                  // 64 MB (32 splits)
    float* l_part = (float*)(ws + (66u << 20));                 // 1 MB

    gat_wh_kernel<<<N_NODES / 16, 256, 0, stream>>>(h, W, a, adj, WhT, src, dst);
    dim3 grid(N_NODES / 64, CSPL);
    gat_attn_kernel<<<grid, 256, 0, stream>>>(adj, WhT, src, dst, O_part, l_part);
    gat_reduce_kernel<<<N_NODES * OUT_F / 256, 256, 0, stream>>>(O_part, l_part, adj, d_out);
}